// Round 2
// baseline (11091.376 us; speedup 1.0000x reference)
//
#include <hip/hip_runtime.h>

// LSTM T=256, B=128, D=512, H=512 — round 2: register-resident weights.
//   grid = 256 blocks (8 row-blocks x 32 col-blocks), 256 threads (4 waves).
//   Block tile: 16 batch rows x 16 hidden units (all 4 gates).
//   Waves K-split: wave w owns k in [w*128,(w+1)*128) of x-half AND h-half.
//   W fragments (4 gates x 8 chunks x 16B/lane = 128 VGPRs) preloaded ONCE.
//   Per step: 4 x-frag loads + 16 x-MFMAs (pre-barrier, overlap poll),
//   grid barrier, 4 h-frag loads + 16 h-MFMAs, LDS partial reduce (4 waves),
//   per-thread gate nonlinearity (1 element/thread, s in register), store.

#define TT 256
#define BB 128
#define DD 512
#define HH 512
#define KK 1024
#define NBLK 256

typedef __bf16 bf16x8 __attribute__((ext_vector_type(8)));
typedef float f32x4 __attribute__((ext_vector_type(4)));
typedef unsigned short u16x8 __attribute__((ext_vector_type(8)));

__device__ __forceinline__ unsigned short f2bf(float f) {
  unsigned b = __builtin_bit_cast(unsigned, f);
  return (unsigned short)((b + 0x7fffu + ((b >> 16) & 1u)) >> 16);
}
__device__ __forceinline__ float fexp(float x) {
  return __builtin_amdgcn_exp2f(x * 1.4426950408889634f);
}
__device__ __forceinline__ float fsig(float x) {
  return __builtin_amdgcn_rcpf(1.0f + fexp(-x));
}
__device__ __forceinline__ float ftanh(float x) {
  return 2.0f * fsig(2.0f * x) - 1.0f;
}

// ---- prep: X fp32 -> bf16 (RNE), 8 elems/thread ----
__global__ __launch_bounds__(256) void convert_x_kernel(const float* __restrict__ X,
                                                        unsigned short* __restrict__ Xbf) {
  size_t i = (size_t)blockIdx.x * 256 + threadIdx.x;
  const float4* src = (const float4*)X + i * 2;
  float4 v0 = src[0], v1 = src[1];
  u16x8 o;
  o[0] = f2bf(v0.x); o[1] = f2bf(v0.y); o[2] = f2bf(v0.z); o[3] = f2bf(v0.w);
  o[4] = f2bf(v1.x); o[5] = f2bf(v1.y); o[6] = f2bf(v1.z); o[7] = f2bf(v1.w);
  ((u16x8*)Xbf)[i] = o;
}

// ---- prep: build WT[g][k] bf16, g = q*512 + j; k<512 from Wq_x[k][j], else Wq_h[k-512][j].
__global__ __launch_bounds__(256) void build_wt_kernel(
    const float* __restrict__ Wax, const float* __restrict__ Wix,
    const float* __restrict__ Wfx, const float* __restrict__ Wox,
    const float* __restrict__ Wah, const float* __restrict__ Wih,
    const float* __restrict__ Wfh, const float* __restrict__ Woh,
    unsigned short* __restrict__ WT) {
  __shared__ float tile[64][65];
  int bid = blockIdx.x;           // q*128 + jt*16 + kt
  int q  = bid >> 7;
  int jt = (bid >> 4) & 7;
  int kt = bid & 15;
  const float* Wx[4] = {Wax, Wix, Wfx, Wox};
  const float* Wh[4] = {Wah, Wih, Wfh, Woh};
  const float* src = (kt < 8) ? Wx[q] : Wh[q];
  int k0 = (kt & 7) * 64;
  int j0 = jt * 64;
  int tid = threadIdx.x;
#pragma unroll
  for (int e = 0; e < 16; ++e) {
    int lin = e * 256 + tid;
    int kk = lin >> 6, jj = lin & 63;
    tile[kk][jj] = src[(size_t)(k0 + kk) * HH + j0 + jj];
  }
  __syncthreads();
#pragma unroll
  for (int e = 0; e < 16; ++e) {
    int lin = e * 256 + tid;
    int jj = lin >> 6, kk = lin & 63;
    WT[(size_t)(q * HH + j0 + jj) * KK + kt * 64 + kk] = f2bf(tile[kk][jj]);
  }
}

// ---- main persistent recurrence kernel ----
__global__ __launch_bounds__(256, 1) void lstm_main(
    const unsigned short* __restrict__ Xbf,
    const unsigned short* __restrict__ WT,
    const float* __restrict__ ba, const float* __restrict__ bi,
    const float* __restrict__ bfg, const float* __restrict__ bo,
    unsigned short* __restrict__ hbuf,
    float* __restrict__ out,
    int* __restrict__ flags) {
  const int tid  = threadIdx.x;
  const int bid  = blockIdx.x;
  const int lane = tid & 63;
  const int wave = tid >> 6;
  const int rb = bid >> 5;            // 0..7  (16 batch rows)
  const int cb = bid & 31;            // 0..31 (16 hidden units)
  const int l15 = lane & 15;
  const int lk8 = (lane >> 4) * 8;    // k offset within a 32-chunk
  const int rbase = rb * 16;
  const int colg = cb * 16 + l15;     // hidden index for B-fragments
  const int wk = wave * 128;          // this wave's K-slice base (within each half)

  // ---- preload W fragments into registers (constant across all timesteps) ----
  bf16x8 wf[4][8];
#pragma unroll
  for (int g = 0; g < 4; ++g) {
    const unsigned short* wg = WT + (size_t)(g * HH + colg) * KK + lk8;
#pragma unroll
    for (int c = 0; c < 8; ++c) {
      int kb = (c < 4) ? (wk + c * 32) : (DD + wk + (c - 4) * 32);
      wf[g][c] = *(const bf16x8*)(wg + kb);
    }
  }

  // per-thread output element (reduce phase): row = tid>>4, col = tid&15
  const int el_row = tid >> 4;
  const int el_col = tid & 15;
  const int el_colg = cb * 16 + el_col;
  const int el_rowg = rbase + el_row;
  const float b0 = ba[el_colg], b1 = bi[el_colg], b2 = bfg[el_colg], b3 = bo[el_colg];
  const int lsrc = (el_row >> 2) * 16 + el_col;  // source lane in C-fragment
  const int rsrc = el_row & 3;                   // source reg in C-fragment

  const unsigned short* xbase = Xbf + (size_t)(rbase + l15) * DD + wk + lk8;
  const size_t hrow = (size_t)(rbase + l15) * HH + wk + lk8;

  __shared__ f32x4 part[2][4][4][64];   // [buf][wave][gate][lane]

  float s_c = 0.f;   // cell state for this thread's element

  for (int t = 0; t < TT; ++t) {
    // ---- x-projection part (independent of barrier) ----
    bf16x8 ax0 = *(const bf16x8*)(xbase + (size_t)t * BB * DD);
    bf16x8 ax1 = *(const bf16x8*)(xbase + (size_t)t * BB * DD + 32);
    bf16x8 ax2 = *(const bf16x8*)(xbase + (size_t)t * BB * DD + 64);
    bf16x8 ax3 = *(const bf16x8*)(xbase + (size_t)t * BB * DD + 96);

    f32x4 acc[4];
#pragma unroll
    for (int g = 0; g < 4; ++g) {
      f32x4 z = {0.f, 0.f, 0.f, 0.f};
      acc[g] = __builtin_amdgcn_mfma_f32_16x16x32_bf16(ax0, wf[g][0], z, 0, 0, 0);
      acc[g] = __builtin_amdgcn_mfma_f32_16x16x32_bf16(ax1, wf[g][1], acc[g], 0, 0, 0);
      acc[g] = __builtin_amdgcn_mfma_f32_16x16x32_bf16(ax2, wf[g][2], acc[g], 0, 0, 0);
      acc[g] = __builtin_amdgcn_mfma_f32_16x16x32_bf16(ax3, wf[g][3], acc[g], 0, 0, 0);
    }

    // ---- wait for h_{t-1} (wave 0 polls all 256 block flags) ----
    if (wave == 0 && t > 0) {
      int mn;
      do {
        int v0 = __hip_atomic_load(&flags[(lane      ) * 16], __ATOMIC_ACQUIRE, __HIP_MEMORY_SCOPE_AGENT);
        int v1 = __hip_atomic_load(&flags[(lane +  64) * 16], __ATOMIC_ACQUIRE, __HIP_MEMORY_SCOPE_AGENT);
        int v2 = __hip_atomic_load(&flags[(lane + 128) * 16], __ATOMIC_ACQUIRE, __HIP_MEMORY_SCOPE_AGENT);
        int v3 = __hip_atomic_load(&flags[(lane + 192) * 16], __ATOMIC_ACQUIRE, __HIP_MEMORY_SCOPE_AGENT);
        mn = min(min(v0, v1), min(v2, v3));
        if (__any(mn < t)) { __builtin_amdgcn_s_sleep(1); mn = -1; }
      } while (mn < 0);
    }
    __syncthreads();
    __threadfence();

    // ---- h part ----
    const unsigned short* hp = hbuf + (size_t)((t & 1) ^ 1) * BB * HH + hrow;
    bf16x8 ah0 = *(const bf16x8*)(hp);
    bf16x8 ah1 = *(const bf16x8*)(hp + 32);
    bf16x8 ah2 = *(const bf16x8*)(hp + 64);
    bf16x8 ah3 = *(const bf16x8*)(hp + 96);
#pragma unroll
    for (int g = 0; g < 4; ++g) {
      acc[g] = __builtin_amdgcn_mfma_f32_16x16x32_bf16(ah0, wf[g][4], acc[g], 0, 0, 0);
      acc[g] = __builtin_amdgcn_mfma_f32_16x16x32_bf16(ah1, wf[g][5], acc[g], 0, 0, 0);
      acc[g] = __builtin_amdgcn_mfma_f32_16x16x32_bf16(ah2, wf[g][6], acc[g], 0, 0, 0);
      acc[g] = __builtin_amdgcn_mfma_f32_16x16x32_bf16(ah3, wf[g][7], acc[g], 0, 0, 0);
    }

    // ---- write K-partials to LDS ----
    const int pb = t & 1;
#pragma unroll
    for (int g = 0; g < 4; ++g) part[pb][wave][g][lane] = acc[g];
    __syncthreads();

    // ---- per-thread reduce over 4 waves + gate nonlinearity (1 element/thread) ----
    float g0 = b0, g1 = b1, g2 = b2, g3 = b3;
#pragma unroll
    for (int w = 0; w < 4; ++w) {
      g0 += ((const float*)&part[pb][w][0][lsrc])[rsrc];
      g1 += ((const float*)&part[pb][w][1][lsrc])[rsrc];
      g2 += ((const float*)&part[pb][w][2][lsrc])[rsrc];
      g3 += ((const float*)&part[pb][w][3][lsrc])[rsrc];
    }
    float av = ftanh(g0);
    float iv = fsig(g1);
    float fv = fsig(g2);
    float ov = fsig(g3);
    s_c = av * iv + s_c * fv;
    float hv = ftanh(s_c) * ov;

    out[(size_t)t * BB * HH + (size_t)el_rowg * HH + el_colg] = hv;
    hbuf[(size_t)(t & 1) * BB * HH + (size_t)el_rowg * HH + el_colg] = f2bf(hv);

    if (t == TT - 1) break;

    __syncthreads();
    if (tid == 0) {
      __threadfence();
      __hip_atomic_store(&flags[bid * 16], t + 1, __ATOMIC_RELEASE, __HIP_MEMORY_SCOPE_AGENT);
    }
  }
}

extern "C" void kernel_launch(void* const* d_in, const int* in_sizes, int n_in,
                              void* d_out, int out_size, void* d_ws, size_t ws_size,
                              hipStream_t stream) {
  const float* X   = (const float*)d_in[0];
  const float* Wax = (const float*)d_in[1];
  const float* Wix = (const float*)d_in[2];
  const float* Wfx = (const float*)d_in[3];
  const float* Wox = (const float*)d_in[4];
  const float* Wah = (const float*)d_in[5];
  const float* Wih = (const float*)d_in[6];
  const float* Wfh = (const float*)d_in[7];
  const float* Woh = (const float*)d_in[8];
  const float* ba  = (const float*)d_in[9];
  const float* bi  = (const float*)d_in[10];
  const float* bf  = (const float*)d_in[11];
  const float* bo  = (const float*)d_in[12];
  float* out = (float*)d_out;

  char* ws = (char*)d_ws;
  unsigned short* Xbf  = (unsigned short*)ws;                               // 33,554,432 B
  unsigned short* WT   = (unsigned short*)(ws + 33554432);                  //  4,194,304 B
  unsigned short* hbuf = (unsigned short*)(ws + 33554432 + 4194304);        //    262,144 B
  int* flags           = (int*)(ws + 33554432 + 4194304 + 262144);          //     16,384 B

  // zero h_{-1} (both parity buffers) and barrier flags every launch
  hipMemsetAsync(hbuf, 0, 262144 + 16384, stream);

  convert_x_kernel<<<8192, 256, 0, stream>>>(X, Xbf);
  build_wt_kernel<<<512, 256, 0, stream>>>(Wax, Wix, Wfx, Wox, Wah, Wih, Wfh, Woh, WT);
  lstm_main<<<NBLK, 256, 0, stream>>>(Xbf, WT, ba, bi, bf, bo, hbuf, out, flags);
}

// Round 3
// 780.686 us; speedup vs baseline: 14.2072x; 14.2072x over previous
//
#include <hip/hip_runtime.h>

// LSTM T=256, B=128, D=512, H=512 — round 3: group-scoped lock-free sync.
//   grid = 256 blocks (8 row-groups x 32 col-blocks), 256 threads (4 waves).
//   Block tile: 16 batch rows x 16 hidden units (all 4 gates).
//   Waves K-split: wave w owns k in [w*128,(w+1)*128) of x-half AND h-half.
//   W fragments (4 gates x 8 chunks = 128 regs) preloaded ONCE (unified VGPR/AGPR).
//   Sync: only the 32 blocks sharing batch rows rb sync, via one counter per
//   (rb, t). h crosses XCDs through agent-scope RELAXED atomics (sc1 path ->
//   coherent LLC). NO __threadfence (no L2 writeback/invalidate storms).

#define TT 256
#define BB 128
#define DD 512
#define HH 512
#define KK 1024
#define NBLK 256

typedef __bf16 bf16x8 __attribute__((ext_vector_type(8)));
typedef float f32x4 __attribute__((ext_vector_type(4)));
typedef unsigned short u16x8 __attribute__((ext_vector_type(8)));
typedef unsigned long long u64;

union h128 { u64 q[2]; bf16x8 v; };

__device__ __forceinline__ unsigned short f2bf(float f) {
  unsigned b = __builtin_bit_cast(unsigned, f);
  return (unsigned short)((b + 0x7fffu + ((b >> 16) & 1u)) >> 16);
}
__device__ __forceinline__ float fexp(float x) {
  return __builtin_amdgcn_exp2f(x * 1.4426950408889634f);
}
__device__ __forceinline__ float fsig(float x) {
  return __builtin_amdgcn_rcpf(1.0f + fexp(-x));
}
__device__ __forceinline__ float ftanh(float x) {
  return 2.0f * fsig(2.0f * x) - 1.0f;
}

// ---- prep: X fp32 -> bf16 (RNE), 8 elems/thread ----
__global__ __launch_bounds__(256) void convert_x_kernel(const float* __restrict__ X,
                                                        unsigned short* __restrict__ Xbf) {
  size_t i = (size_t)blockIdx.x * 256 + threadIdx.x;
  const float4* src = (const float4*)X + i * 2;
  float4 v0 = src[0], v1 = src[1];
  u16x8 o;
  o[0] = f2bf(v0.x); o[1] = f2bf(v0.y); o[2] = f2bf(v0.z); o[3] = f2bf(v0.w);
  o[4] = f2bf(v1.x); o[5] = f2bf(v1.y); o[6] = f2bf(v1.z); o[7] = f2bf(v1.w);
  ((u16x8*)Xbf)[i] = o;
}

// ---- prep: build WT[g][k] bf16, g = q*512 + j; k<512 from Wq_x[k][j], else Wq_h[k-512][j].
__global__ __launch_bounds__(256) void build_wt_kernel(
    const float* __restrict__ Wax, const float* __restrict__ Wix,
    const float* __restrict__ Wfx, const float* __restrict__ Wox,
    const float* __restrict__ Wah, const float* __restrict__ Wih,
    const float* __restrict__ Wfh, const float* __restrict__ Woh,
    unsigned short* __restrict__ WT) {
  __shared__ float tile[64][65];
  int bid = blockIdx.x;           // q*128 + jt*16 + kt
  int q  = bid >> 7;
  int jt = (bid >> 4) & 7;
  int kt = bid & 15;
  const float* Wx[4] = {Wax, Wix, Wfx, Wox};
  const float* Wh[4] = {Wah, Wih, Wfh, Woh};
  const float* src = (kt < 8) ? Wx[q] : Wh[q];
  int k0 = (kt & 7) * 64;
  int j0 = jt * 64;
  int tid = threadIdx.x;
#pragma unroll
  for (int e = 0; e < 16; ++e) {
    int lin = e * 256 + tid;
    int kk = lin >> 6, jj = lin & 63;
    tile[kk][jj] = src[(size_t)(k0 + kk) * HH + j0 + jj];
  }
  __syncthreads();
#pragma unroll
  for (int e = 0; e < 16; ++e) {
    int lin = e * 256 + tid;
    int jj = lin >> 6, kk = lin & 63;
    WT[(size_t)(q * HH + j0 + jj) * KK + kt * 64 + kk] = f2bf(tile[kk][jj]);
  }
}

// ---- main persistent recurrence kernel ----
__global__ __launch_bounds__(256, 1) void lstm_main(
    const unsigned short* __restrict__ Xbf,
    const unsigned short* __restrict__ WT,
    const float* __restrict__ ba, const float* __restrict__ bi,
    const float* __restrict__ bfg, const float* __restrict__ bo,
    unsigned short* __restrict__ hbuf,
    float* __restrict__ out,
    int* __restrict__ cnt) {
  const int tid  = threadIdx.x;
  const int bid  = blockIdx.x;
  const int lane = tid & 63;
  const int wave = tid >> 6;
  const int rb = bid >> 5;            // 0..7  (16 batch rows) — sync group
  const int cb = bid & 31;            // 0..31 (16 hidden units)
  const int l15 = lane & 15;
  const int lk8 = (lane >> 4) * 8;    // k offset within a 32-chunk
  const int rbase = rb * 16;
  const int colg = cb * 16 + l15;     // hidden index for B-fragments
  const int wk = wave * 128;          // this wave's K-slice base (within each half)

  // ---- preload W fragments (constant across all timesteps) ----
  bf16x8 wf[4][8];
#pragma unroll
  for (int g = 0; g < 4; ++g) {
    const unsigned short* wg = WT + (size_t)(g * HH + colg) * KK + lk8;
#pragma unroll
    for (int c = 0; c < 8; ++c) {
      int kb = (c < 4) ? (wk + c * 32) : (DD + wk + (c - 4) * 32);
      wf[g][c] = *(const bf16x8*)(wg + kb);
    }
  }

  // per-thread output element (reduce phase): row = tid>>4, col = tid&15
  const int el_row = tid >> 4;
  const int el_col = tid & 15;
  const int el_colg = cb * 16 + el_col;
  const int el_rowg = rbase + el_row;
  const float b0 = ba[el_colg], b1 = bi[el_colg], b2 = bfg[el_colg], b3 = bo[el_colg];
  const int lsrc = (el_row >> 2) * 16 + el_col;  // source lane in C-fragment
  const int rsrc = el_row & 3;                   // source reg in C-fragment

  const unsigned short* xbase = Xbf + (size_t)(rbase + l15) * DD + wk + lk8;
  const size_t hrow = (size_t)(rbase + l15) * HH + wk + lk8;   // element offset
  const size_t hstore_el = (size_t)el_rowg * HH + el_colg;     // element offset

  __shared__ f32x4 part[2][4][4][64];   // [buf][wave][gate][lane]

  float s_c = 0.f;   // cell state for this thread's element

  for (int t = 0; t < TT; ++t) {
    // ---- x-projection part (no cross-block dependency) ----
    const unsigned short* xt = xbase + (size_t)t * BB * DD;
    bf16x8 ax0 = *(const bf16x8*)(xt);
    bf16x8 ax1 = *(const bf16x8*)(xt + 32);
    bf16x8 ax2 = *(const bf16x8*)(xt + 64);
    bf16x8 ax3 = *(const bf16x8*)(xt + 96);

    f32x4 acc[4];
#pragma unroll
    for (int g = 0; g < 4; ++g) {
      f32x4 z = {0.f, 0.f, 0.f, 0.f};
      acc[g] = __builtin_amdgcn_mfma_f32_16x16x32_bf16(ax0, wf[g][0], z, 0, 0, 0);
      acc[g] = __builtin_amdgcn_mfma_f32_16x16x32_bf16(ax1, wf[g][1], acc[g], 0, 0, 0);
      acc[g] = __builtin_amdgcn_mfma_f32_16x16x32_bf16(ax2, wf[g][2], acc[g], 0, 0, 0);
      acc[g] = __builtin_amdgcn_mfma_f32_16x16x32_bf16(ax3, wf[g][3], acc[g], 0, 0, 0);
    }

    // ---- wait for group peers to publish h_{t-1} ----
    if (t > 0) {
      if (tid == 0) {
        while (__hip_atomic_load(&cnt[rb * TT + (t - 1)], __ATOMIC_RELAXED,
                                 __HIP_MEMORY_SCOPE_AGENT) < 32) {}
      }
      __syncthreads();
    }

    // ---- h part: agent-scope relaxed loads (coherent LLC path) ----
    const u64* hp = (const u64*)(hbuf + (size_t)((t & 1) ^ 1) * BB * HH + hrow);
    h128 u0, u1, u2, u3;
    u0.q[0] = __hip_atomic_load(hp +  0, __ATOMIC_RELAXED, __HIP_MEMORY_SCOPE_AGENT);
    u0.q[1] = __hip_atomic_load(hp +  1, __ATOMIC_RELAXED, __HIP_MEMORY_SCOPE_AGENT);
    u1.q[0] = __hip_atomic_load(hp +  8, __ATOMIC_RELAXED, __HIP_MEMORY_SCOPE_AGENT);
    u1.q[1] = __hip_atomic_load(hp +  9, __ATOMIC_RELAXED, __HIP_MEMORY_SCOPE_AGENT);
    u2.q[0] = __hip_atomic_load(hp + 16, __ATOMIC_RELAXED, __HIP_MEMORY_SCOPE_AGENT);
    u2.q[1] = __hip_atomic_load(hp + 17, __ATOMIC_RELAXED, __HIP_MEMORY_SCOPE_AGENT);
    u3.q[0] = __hip_atomic_load(hp + 24, __ATOMIC_RELAXED, __HIP_MEMORY_SCOPE_AGENT);
    u3.q[1] = __hip_atomic_load(hp + 25, __ATOMIC_RELAXED, __HIP_MEMORY_SCOPE_AGENT);

#pragma unroll
    for (int g = 0; g < 4; ++g) {
      acc[g] = __builtin_amdgcn_mfma_f32_16x16x32_bf16(u0.v, wf[g][4], acc[g], 0, 0, 0);
      acc[g] = __builtin_amdgcn_mfma_f32_16x16x32_bf16(u1.v, wf[g][5], acc[g], 0, 0, 0);
      acc[g] = __builtin_amdgcn_mfma_f32_16x16x32_bf16(u2.v, wf[g][6], acc[g], 0, 0, 0);
      acc[g] = __builtin_amdgcn_mfma_f32_16x16x32_bf16(u3.v, wf[g][7], acc[g], 0, 0, 0);
    }

    // ---- write K-partials to LDS ----
    const int pb = t & 1;
#pragma unroll
    for (int g = 0; g < 4; ++g) part[pb][wave][g][lane] = acc[g];
    __syncthreads();

    // ---- per-thread reduce over 4 waves + gate nonlinearity ----
    float g0 = b0, g1 = b1, g2 = b2, g3 = b3;
#pragma unroll
    for (int w = 0; w < 4; ++w) {
      g0 += ((const float*)&part[pb][w][0][lsrc])[rsrc];
      g1 += ((const float*)&part[pb][w][1][lsrc])[rsrc];
      g2 += ((const float*)&part[pb][w][2][lsrc])[rsrc];
      g3 += ((const float*)&part[pb][w][3][lsrc])[rsrc];
    }
    float av = ftanh(g0);
    float iv = fsig(g1);
    float fv = fsig(g2);
    float ov = fsig(g3);
    s_c = av * iv + s_c * fv;
    float hv = ftanh(s_c) * ov;

    out[(size_t)t * BB * HH + hstore_el] = hv;

    // ---- publish h: pack 2 bf16 per u32, agent-scope relaxed store ----
    unsigned mybf = (unsigned)f2bf(hv);
    unsigned nxbf = (unsigned)__shfl_down((int)mybf, 1);
    if ((tid & 1) == 0) {
      unsigned pack = mybf | (nxbf << 16);
      unsigned* dst = (unsigned*)(hbuf + (size_t)pb * BB * HH + hstore_el);
      __hip_atomic_store(dst, pack, __ATOMIC_RELAXED, __HIP_MEMORY_SCOPE_AGENT);
    }

    if (t == TT - 1) break;

    // __syncthreads drains all waves' stores (compiler emits s_waitcnt vmcnt(0)
    // before s_barrier), so the sc1 h-stores are acknowledged at the coherence
    // point before the counter bump.
    __syncthreads();
    if (tid == 0) {
      __hip_atomic_fetch_add(&cnt[rb * TT + t], 1, __ATOMIC_RELAXED,
                             __HIP_MEMORY_SCOPE_AGENT);
    }
  }
}

extern "C" void kernel_launch(void* const* d_in, const int* in_sizes, int n_in,
                              void* d_out, int out_size, void* d_ws, size_t ws_size,
                              hipStream_t stream) {
  const float* X   = (const float*)d_in[0];
  const float* Wax = (const float*)d_in[1];
  const float* Wix = (const float*)d_in[2];
  const float* Wfx = (const float*)d_in[3];
  const float* Wox = (const float*)d_in[4];
  const float* Wah = (const float*)d_in[5];
  const float* Wih = (const float*)d_in[6];
  const float* Wfh = (const float*)d_in[7];
  const float* Woh = (const float*)d_in[8];
  const float* ba  = (const float*)d_in[9];
  const float* bi  = (const float*)d_in[10];
  const float* bf  = (const float*)d_in[11];
  const float* bo  = (const float*)d_in[12];
  float* out = (float*)d_out;

  char* ws = (char*)d_ws;
  unsigned short* Xbf  = (unsigned short*)ws;                               // 33,554,432 B
  unsigned short* WT   = (unsigned short*)(ws + 33554432);                  //  4,194,304 B
  unsigned short* hbuf = (unsigned short*)(ws + 33554432 + 4194304);        //    262,144 B
  int* cnt             = (int*)(ws + 33554432 + 4194304 + 262144);          //      8,192 B

  // zero h_{-1} (both parity buffers) and step counters every launch
  hipMemsetAsync(hbuf, 0, 262144 + 8192, stream);

  convert_x_kernel<<<8192, 256, 0, stream>>>(X, Xbf);
  build_wt_kernel<<<512, 256, 0, stream>>>(Wax, Wix, Wfx, Wox, Wah, Wih, Wfh, Woh, WT);
  lstm_main<<<NBLK, 256, 0, stream>>>(Xbf, WT, ba, bi, bf, bo, hbuf, out, cnt);
}